// Round 5
// baseline (652.816 us; speedup 1.0000x reference)
//
#include <hip/hip_runtime.h>
#include <hip/hip_bf16.h>
#include <cstdint>

typedef __bf16 bf16;
typedef bf16 bf16x8 __attribute__((ext_vector_type(8)));
typedef bf16 bf16x4 __attribute__((ext_vector_type(4)));
typedef float f32x4 __attribute__((ext_vector_type(4)));

#define N_TOK 4096
#define DIM   1024
#define HID   4096
#define OUTD  1024
#define NEXP  8

// ---------------------------------------------------------------- helpers
__device__ __forceinline__ void async_copy16(const void* g, void* l) {
  __builtin_amdgcn_global_load_lds(
      (const __attribute__((address_space(1))) void*)g,
      (__attribute__((address_space(3))) void*)l, 16, 0, 0);
}

// stage one 128x64 bf16 tile (16 KB): 4 async_copy16/thread.
// chunk c = wave*4+i covers rows 8c..8c+7; lane: crow=lane>>3 row, slot=lane&7.
// LDS dest is linear; bank-swizzle comes from the pre-swizzled global k-slot
// (slot ^ crow) -- verified conflict-free in R3 (SQ_LDS_BANK_CONFLICT == 0).
__device__ __forceinline__ void stage_tile(
    const bf16* pA0, const bf16* pA1, const bf16* pA2, const bf16* pA3,
    const bf16* pB0, const bf16* pB1, const bf16* pB2, const bf16* pB3,
    bf16* lA, bf16* lB, int ko, int wave)
{
  async_copy16(pA0 + ko, lA + (wave * 4 + 0) * 512);
  async_copy16(pA1 + ko, lA + (wave * 4 + 1) * 512);
  async_copy16(pA2 + ko, lA + (wave * 4 + 2) * 512);
  async_copy16(pA3 + ko, lA + (wave * 4 + 3) * 512);
  async_copy16(pB0 + ko, lB + (wave * 4 + 0) * 512);
  async_copy16(pB1 + ko, lB + (wave * 4 + 1) * 512);
  async_copy16(pB2 + ko, lB + (wave * 4 + 2) * 512);
  async_copy16(pB3 + ko, lB + (wave * 4 + 3) * 512);
}

// ---------------------------------------------------------------- gating
__global__ __launch_bounds__(256) void gate_kernel(
    const float* __restrict__ x, const float* __restrict__ Wg,
    const float* __restrict__ bg, int* __restrict__ topE, float* __restrict__ topW)
{
  int wave = threadIdx.x >> 6, lane = threadIdx.x & 63;
  int t = blockIdx.x * 4 + wave;
  float acc[8];
#pragma unroll
  for (int e = 0; e < 8; ++e) acc[e] = 0.f;
  const float* xrow = x + (size_t)t * DIM;
#pragma unroll
  for (int i = 0; i < DIM / 64; ++i) {
    int d = i * 64 + lane;
    float xv = xrow[d];
    float4 w0 = *(const float4*)(Wg + d * 8);
    float4 w1 = *(const float4*)(Wg + d * 8 + 4);
    acc[0] += xv * w0.x; acc[1] += xv * w0.y; acc[2] += xv * w0.z; acc[3] += xv * w0.w;
    acc[4] += xv * w1.x; acc[5] += xv * w1.y; acc[6] += xv * w1.z; acc[7] += xv * w1.w;
  }
#pragma unroll
  for (int off = 32; off > 0; off >>= 1) {
#pragma unroll
    for (int e = 0; e < 8; ++e) acc[e] += __shfl_xor(acc[e], off, 64);
  }
  if (lane == 0) {
    float l[8];
#pragma unroll
    for (int e = 0; e < 8; ++e) l[e] = acc[e] + bg[e];
    int e1 = 0;
#pragma unroll
    for (int e = 1; e < 8; ++e) if (l[e] > l[e1]) e1 = e;
    int e2 = (e1 == 0) ? 1 : 0;
#pragma unroll
    for (int e = 0; e < 8; ++e) if (e != e1 && l[e] > l[e2]) e2 = e;
    float w1 = 1.f / (1.f + __expf(l[e2] - l[e1]));
    topE[t * 2] = e1; topE[t * 2 + 1] = e2;
    topW[t * 2] = w1; topW[t * 2 + 1] = 1.f - w1;
  }
}

// ---------------------------------------------------------------- routing lists
__global__ __launch_bounds__(256) void build_lists(
    const int* __restrict__ topE, const float* __restrict__ topW,
    int* __restrict__ cnt, int* __restrict__ tok_list, float* __restrict__ w_list,
    int* __restrict__ inv)
{
  __shared__ int lcnt[8], lbase[8];
  int tid = threadIdx.x;
  if (tid < 8) lcnt[tid] = 0;
  __syncthreads();
  int t = blockIdx.x * 256 + tid;
  int e1 = topE[2 * t], e2 = topE[2 * t + 1];
  float w1 = topW[2 * t], w2 = topW[2 * t + 1];
  int p1 = atomicAdd(&lcnt[e1], 1);
  int p2 = atomicAdd(&lcnt[e2], 1);
  __syncthreads();
  if (tid < 8) lbase[tid] = atomicAdd(&cnt[tid], lcnt[tid]);
  __syncthreads();
  int i1 = e1 * N_TOK + lbase[e1] + p1;
  int i2 = e2 * N_TOK + lbase[e2] + p2;
  tok_list[i1] = t; w_list[i1] = w1;
  tok_list[i2] = t; w_list[i2] = w2;
  inv[2 * t] = i1;
  inv[2 * t + 1] = i2;
}

__global__ void scan_kernel(const int* __restrict__ cnt, int* __restrict__ base)
{
  if (threadIdx.x == 0) {
    int s = 0;
    for (int e = 0; e < 8; ++e) { base[e] = s; s += cnt[e]; }
    base[8] = s;
  }
}

// ---------------------------------------------------------------- gather x rows -> bf16 slots
__global__ __launch_bounds__(256) void gather_cvt(
    const float* __restrict__ x, const int* __restrict__ tok_list,
    const int* __restrict__ base, bf16* __restrict__ xg)
{
  int wave = threadIdx.x >> 6, lane = threadIdx.x & 63;
  int s = blockIdx.x * 4 + wave;
  int e = 0;
#pragma unroll
  for (int i = 1; i < 8; ++i) e += (s >= base[i]);
  int tok = tok_list[e * N_TOK + (s - base[e])];
  const float4* src = (const float4*)(x + (size_t)tok * DIM);
  bf16x4* dst = (bf16x4*)(xg + (size_t)s * DIM);
#pragma unroll
  for (int i = 0; i < DIM / 256; ++i) {
    float4 v = src[i * 64 + lane];
    bf16x4 o;
    o.x = (bf16)v.x; o.y = (bf16)v.y; o.z = (bf16)v.z; o.w = (bf16)v.w;
    dst[i * 64 + lane] = o;
  }
}

// ---------------------------------------------------------------- transpose + f32->bf16
// src: [E][R][C] f32 -> dst: [E][C][R] bf16 ; pad 68 so read side is ds_read_b64
__global__ __launch_bounds__(256) void transpose_cvt(
    const float* __restrict__ src, bf16* __restrict__ dst, int R, int C)
{
  __shared__ bf16 tile[64][68];
  int e = blockIdx.z;
  const float* s = src + (size_t)e * R * C;
  bf16* d = dst + (size_t)e * R * C;
  int c0 = blockIdx.x * 64, r0 = blockIdx.y * 64;
  int tid = threadIdx.x;
  int rr = tid >> 4;          // 0..15
  int cc = (tid & 15) * 4;    // 0,4,..,60
#pragma unroll
  for (int i = 0; i < 4; ++i) {
    int r = i * 16 + rr;
    float4 v = *(const float4*)(s + (size_t)(r0 + r) * C + c0 + cc);
    tile[cc + 0][r] = (bf16)v.x;
    tile[cc + 1][r] = (bf16)v.y;
    tile[cc + 2][r] = (bf16)v.z;
    tile[cc + 3][r] = (bf16)v.w;
  }
  __syncthreads();
#pragma unroll
  for (int i = 0; i < 4; ++i) {
    int ct = i * 16 + rr;
    bf16x4 o = *(const bf16x4*)&tile[ct][cc];
    *(bf16x4*)(d + (size_t)(c0 + ct) * R + r0 + cc) = o;
  }
}

// ---------------------------------------------------------------- GEMM1: h = relu(xg @ W1t^T + b1)
// 128x128 tile, BK=64, SINGLE-buffered 32KB LDS (occupancy preserved),
// R3-verified conflict-free swizzle: source k-slot ^= row&7, read slot ^= lr&7.
__global__ __launch_bounds__(256) void gemm1_kernel(
    const bf16* __restrict__ xg, const bf16* __restrict__ W1t,
    const float* __restrict__ b1, bf16* __restrict__ hbuf,
    const int* __restrict__ cnt, const int* __restrict__ base)
{
  int e = blockIdx.z;
  int M = cnt[e];
  int mt = blockIdx.y;
  if (mt * 128 >= M) return;
  int nt = blockIdx.x;
  int b0 = base[e];

  __shared__ bf16 As[128 * 64];   // 16 KB
  __shared__ bf16 Bs[128 * 64];   // 16 KB

  int tid = threadIdx.x;
  int wave = tid >> 6, lane = tid & 63;
  int crow = lane >> 3;                       // 0..7 row-in-chunk
  int ck   = ((lane & 7) ^ crow) * 8;         // pre-swizzled k-elem offset

  const bf16* pA[4]; const bf16* pB[4];
#pragma unroll
  for (int i = 0; i < 4; ++i) {
    int ra = (wave * 4 + i) * 8 + crow;       // tile row 0..127
    int lm = min(mt * 128 + ra, M - 1);
    pA[i] = xg + (size_t)(b0 + lm) * DIM + ck;
    pB[i] = W1t + ((size_t)e * HID + nt * 128 + ra) * DIM + ck;
  }

  int wm = wave & 1, wn = wave >> 1;
  int quad = lane >> 4, lr = lane & 15;
  int sw = lr & 7;                            // read-side swizzle key (row&7 == lr&7)
  f32x4 acc[4][4] = {};

  for (int kt = 0; kt < DIM / 64; ++kt) {
    stage_tile(pA[0], pA[1], pA[2], pA[3], pB[0], pB[1], pB[2], pB[3],
               As, Bs, kt * 64, wave);
    __syncthreads();
#pragma unroll
    for (int kk = 0; kk < 2; ++kk) {
      bf16x8 af[4], bfr[4];
#pragma unroll
      for (int i = 0; i < 4; ++i)
        af[i] = *(const bf16x8*)(As + (wm * 64 + i * 16 + lr) * 64 + (((kk * 4 + quad) ^ sw) * 8));
#pragma unroll
      for (int j = 0; j < 4; ++j)
        bfr[j] = *(const bf16x8*)(Bs + (wn * 64 + j * 16 + lr) * 64 + (((kk * 4 + quad) ^ sw) * 8));
#pragma unroll
      for (int i = 0; i < 4; ++i)
#pragma unroll
        for (int j = 0; j < 4; ++j)
          acc[i][j] = __builtin_amdgcn_mfma_f32_16x16x32_bf16(af[i], bfr[j], acc[i][j], 0, 0, 0);
    }
    __syncthreads();
  }

#pragma unroll
  for (int j = 0; j < 4; ++j) {
    int col = nt * 128 + wn * 64 + j * 16 + lr;
    float bias = b1[e * HID + col];
#pragma unroll
    for (int i = 0; i < 4; ++i) {
#pragma unroll
      for (int r = 0; r < 4; ++r) {
        int lm = mt * 128 + wm * 64 + i * 16 + quad * 4 + r;
        if (lm < M) {
          float v = acc[i][j][r] + bias;
          hbuf[(size_t)(b0 + lm) * HID + col] = (bf16)fmaxf(v, 0.f);
        }
      }
    }
  }
}

// ---------------------------------------------------------------- GEMM2: ybuf[slot] = h[slot] @ W2t^T + b2
// same BK=64 single-buffered swizzled structure; plain f32 stores, no atomics, no split-K
__global__ __launch_bounds__(256) void gemm2_kernel(
    const bf16* __restrict__ hbuf, const bf16* __restrict__ W2t,
    const float* __restrict__ b2, float* __restrict__ ybufA, float* __restrict__ ybufB,
    const int* __restrict__ cnt, const int* __restrict__ base)
{
  int e = blockIdx.z;
  int M = cnt[e];
  int mt = blockIdx.y;
  if (mt * 128 >= M) return;
  int nt = blockIdx.x;
  int b0 = base[e];

  __shared__ bf16 As[128 * 64];
  __shared__ bf16 Bs[128 * 64];

  int tid = threadIdx.x;
  int wave = tid >> 6, lane = tid & 63;
  int crow = lane >> 3;
  int ck   = ((lane & 7) ^ crow) * 8;

  const bf16* pA[4]; const bf16* pB[4];
#pragma unroll
  for (int i = 0; i < 4; ++i) {
    int ra = (wave * 4 + i) * 8 + crow;
    int lm = min(mt * 128 + ra, M - 1);
    pA[i] = hbuf + (size_t)(b0 + lm) * HID + ck;
    pB[i] = W2t + ((size_t)e * OUTD + nt * 128 + ra) * HID + ck;
  }

  int wm = wave & 1, wn = wave >> 1;
  int quad = lane >> 4, lr = lane & 15;
  int sw = lr & 7;
  f32x4 acc[4][4] = {};

  for (int kt = 0; kt < HID / 64; ++kt) {
    stage_tile(pA[0], pA[1], pA[2], pA[3], pB[0], pB[1], pB[2], pB[3],
               As, Bs, kt * 64, wave);
    __syncthreads();
#pragma unroll
    for (int kk = 0; kk < 2; ++kk) {
      bf16x8 af[4], bfr[4];
#pragma unroll
      for (int i = 0; i < 4; ++i)
        af[i] = *(const bf16x8*)(As + (wm * 64 + i * 16 + lr) * 64 + (((kk * 4 + quad) ^ sw) * 8));
#pragma unroll
      for (int j = 0; j < 4; ++j)
        bfr[j] = *(const bf16x8*)(Bs + (wn * 64 + j * 16 + lr) * 64 + (((kk * 4 + quad) ^ sw) * 8));
#pragma unroll
      for (int i = 0; i < 4; ++i)
#pragma unroll
        for (int j = 0; j < 4; ++j)
          acc[i][j] = __builtin_amdgcn_mfma_f32_16x16x32_bf16(af[i], bfr[j], acc[i][j], 0, 0, 0);
    }
    __syncthreads();
  }

#pragma unroll
  for (int j = 0; j < 4; ++j) {
    int col = nt * 128 + wn * 64 + j * 16 + lr;
    float bias = b2[e * OUTD + col];
#pragma unroll
    for (int i = 0; i < 4; ++i) {
#pragma unroll
      for (int r = 0; r < 4; ++r) {
        int lm = mt * 128 + wm * 64 + i * 16 + quad * 4 + r;
        if (lm < M) {
          int slot = b0 + lm;
          float* yr = (slot < 4096) ? (ybufA + (size_t)slot * OUTD)
                                    : (ybufB + (size_t)(slot - 4096) * OUTD);
          yr[col] = acc[i][j][r] + bias;
        }
      }
    }
  }
}

// ---------------------------------------------------------------- combine: out[t] = w0*y[slot0] + w1*y[slot1]
__global__ __launch_bounds__(256) void combine_kernel(
    const float* __restrict__ ybufA, const float* __restrict__ ybufB,
    const int* __restrict__ inv, const float* __restrict__ topW,
    const int* __restrict__ base, float* __restrict__ out)
{
  int wave = threadIdx.x >> 6, lane = threadIdx.x & 63;
  int t = blockIdx.x * 4 + wave;
  int i0 = inv[2 * t], i1 = inv[2 * t + 1];
  float w0 = topW[2 * t], w1 = topW[2 * t + 1];
  int s0 = base[i0 >> 12] + (i0 & (N_TOK - 1));
  int s1 = base[i1 >> 12] + (i1 & (N_TOK - 1));
  const float4* r0 = (const float4*)((s0 < 4096) ? (ybufA + (size_t)s0 * OUTD)
                                                 : (ybufB + (size_t)(s0 - 4096) * OUTD));
  const float4* r1 = (const float4*)((s1 < 4096) ? (ybufA + (size_t)s1 * OUTD)
                                                 : (ybufB + (size_t)(s1 - 4096) * OUTD));
  float4* o = (float4*)(out + (size_t)t * OUTD);
#pragma unroll
  for (int i = 0; i < OUTD / 256; ++i) {
    float4 a = r0[i * 64 + lane];
    float4 b = r1[i * 64 + lane];
    float4 c;
    c.x = w0 * a.x + w1 * b.x;
    c.y = w0 * a.y + w1 * b.y;
    c.z = w0 * a.z + w1 * b.z;
    c.w = w0 * a.w + w1 * b.w;
    o[i * 64 + lane] = c;
  }
}

// ---------------------------------------------------------------- launch
extern "C" void kernel_launch(void* const* d_in, const int* in_sizes, int n_in,
                              void* d_out, int out_size, void* d_ws, size_t ws_size,
                              hipStream_t stream)
{
  (void)in_sizes; (void)n_in; (void)ws_size; (void)out_size;
  const float* x  = (const float*)d_in[0];
  const float* W1 = (const float*)d_in[1];
  const float* b1 = (const float*)d_in[2];
  const float* W2 = (const float*)d_in[3];
  const float* b2 = (const float*)d_in[4];
  const float* Wg = (const float*)d_in[5];
  const float* bg = (const float*)d_in[6];
  float* out = (float*)d_out;

  char* ws = (char*)d_ws;
  // ws layout (bytes):
  //   0         tok_list   8*4096*4     = 131072
  //   131072    w_list                  = 131072
  //   262144    topE       4096*2*4     = 32768
  //   294912    topW                    = 32768
  //   327680    cnt        (64B pad)
  //   327744    base       (64B pad)
  //   327808    inv        4096*2*4     = 32768
  //   393216    xg         16MB   (ends 17170432)
  //   17170432  W1t        64MB   (ends 84279296)
  //   84279296  hbuf       64MB   (ends 151388160)
  //   W2t overlays [393216, 67502080) -- xg/W1t-head dead after gemm1
  //   ybufA 16MB at 67502080  (W1t tail hole, dead during gemm2)
  //   ybufB 16MB at 151388160 (ends 168165376)
  int*   tok_list = (int*)(ws + 0);
  float* w_list   = (float*)(ws + 131072);
  int*   topE     = (int*)(ws + 262144);
  float* topW     = (float*)(ws + 294912);
  int*   cnt      = (int*)(ws + 327680);
  int*   base     = (int*)(ws + 327744);
  int*   inv      = (int*)(ws + 327808);
  bf16*  xg    = (bf16*)(ws + 393216);
  bf16*  W1t   = (bf16*)(ws + 17170432);
  bf16*  hbuf  = (bf16*)(ws + 84279296);
  bf16*  W2t   = (bf16*)(ws + 393216);
  float* ybufA = (float*)(ws + 67502080);
  float* ybufB = (float*)(ws + 151388160);

  hipMemsetAsync(cnt, 0, 64, stream);

  gate_kernel<<<dim3(N_TOK / 4), 256, 0, stream>>>(x, Wg, bg, topE, topW);
  build_lists<<<dim3(N_TOK / 256), 256, 0, stream>>>(topE, topW, cnt, tok_list, w_list, inv);
  scan_kernel<<<dim3(1), 64, 0, stream>>>(cnt, base);
  gather_cvt<<<dim3(2 * N_TOK / 4), 256, 0, stream>>>(x, tok_list, base, xg);
  transpose_cvt<<<dim3(HID / 64, DIM / 64, NEXP), 256, 0, stream>>>(W1, W1t, DIM, HID);
  gemm1_kernel<<<dim3(HID / 128, N_TOK / 128, NEXP), 256, 0, stream>>>(xg, W1t, b1, hbuf, cnt, base);
  transpose_cvt<<<dim3(OUTD / 64, HID / 64, NEXP), 256, 0, stream>>>(W2, W2t, HID, OUTD);
  gemm2_kernel<<<dim3(OUTD / 128, N_TOK / 128, NEXP), 256, 0, stream>>>(hbuf, W2t, b2, ybufA, ybufB, cnt, base);
  combine_kernel<<<dim3(N_TOK / 4), 256, 0, stream>>>(ybufA, ybufB, inv, topW, base, out);
}

// Round 6
// 642.722 us; speedup vs baseline: 1.0157x; 1.0157x over previous
//
#include <hip/hip_runtime.h>
#include <hip/hip_bf16.h>
#include <cstdint>

typedef __bf16 bf16;
typedef bf16 bf16x8 __attribute__((ext_vector_type(8)));
typedef bf16 bf16x4 __attribute__((ext_vector_type(4)));
typedef float f32x4 __attribute__((ext_vector_type(4)));

#define N_TOK 4096
#define DIM   1024
#define HID   4096
#define OUTD  1024
#define NEXP  8

// ---------------------------------------------------------------- helpers
__device__ __forceinline__ void async_copy16(const void* g, void* l) {
  __builtin_amdgcn_global_load_lds(
      (const __attribute__((address_space(1))) void*)g,
      (__attribute__((address_space(3))) void*)l, 16, 0, 0);
}

// stage one 128x64 bf16 tile (16 KB): 8 async_copy16/thread (4 A + 4 B).
// chunk c = wave*4+i covers rows 8c..8c+7; lane: crow=lane>>3 row, slot=lane&7.
// LDS dest is linear; bank-swizzle comes from the pre-swizzled global k-slot
// (slot ^ crow) -- verified conflict-free in R3/R5 (SQ_LDS_BANK_CONFLICT == 0).
__device__ __forceinline__ void stage_tile(
    const bf16* pA0, const bf16* pA1, const bf16* pA2, const bf16* pA3,
    const bf16* pB0, const bf16* pB1, const bf16* pB2, const bf16* pB3,
    bf16* lA, bf16* lB, int ko, int wave)
{
  async_copy16(pA0 + ko, lA + (wave * 4 + 0) * 512);
  async_copy16(pA1 + ko, lA + (wave * 4 + 1) * 512);
  async_copy16(pA2 + ko, lA + (wave * 4 + 2) * 512);
  async_copy16(pA3 + ko, lA + (wave * 4 + 3) * 512);
  async_copy16(pB0 + ko, lB + (wave * 4 + 0) * 512);
  async_copy16(pB1 + ko, lB + (wave * 4 + 1) * 512);
  async_copy16(pB2 + ko, lB + (wave * 4 + 2) * 512);
  async_copy16(pB3 + ko, lB + (wave * 4 + 3) * 512);
}

// ---------------------------------------------------------------- gating
__global__ __launch_bounds__(256) void gate_kernel(
    const float* __restrict__ x, const float* __restrict__ Wg,
    const float* __restrict__ bg, int* __restrict__ topE, float* __restrict__ topW)
{
  int wave = threadIdx.x >> 6, lane = threadIdx.x & 63;
  int t = blockIdx.x * 4 + wave;
  float acc[8];
#pragma unroll
  for (int e = 0; e < 8; ++e) acc[e] = 0.f;
  const float* xrow = x + (size_t)t * DIM;
#pragma unroll
  for (int i = 0; i < DIM / 64; ++i) {
    int d = i * 64 + lane;
    float xv = xrow[d];
    float4 w0 = *(const float4*)(Wg + d * 8);
    float4 w1 = *(const float4*)(Wg + d * 8 + 4);
    acc[0] += xv * w0.x; acc[1] += xv * w0.y; acc[2] += xv * w0.z; acc[3] += xv * w0.w;
    acc[4] += xv * w1.x; acc[5] += xv * w1.y; acc[6] += xv * w1.z; acc[7] += xv * w1.w;
  }
#pragma unroll
  for (int off = 32; off > 0; off >>= 1) {
#pragma unroll
    for (int e = 0; e < 8; ++e) acc[e] += __shfl_xor(acc[e], off, 64);
  }
  if (lane == 0) {
    float l[8];
#pragma unroll
    for (int e = 0; e < 8; ++e) l[e] = acc[e] + bg[e];
    int e1 = 0;
#pragma unroll
    for (int e = 1; e < 8; ++e) if (l[e] > l[e1]) e1 = e;
    int e2 = (e1 == 0) ? 1 : 0;
#pragma unroll
    for (int e = 0; e < 8; ++e) if (e != e1 && l[e] > l[e2]) e2 = e;
    float w1 = 1.f / (1.f + __expf(l[e2] - l[e1]));
    topE[t * 2] = e1; topE[t * 2 + 1] = e2;
    topW[t * 2] = w1; topW[t * 2 + 1] = 1.f - w1;
  }
}

// ---------------------------------------------------------------- routing lists
__global__ __launch_bounds__(256) void build_lists(
    const int* __restrict__ topE, const float* __restrict__ topW,
    int* __restrict__ cnt, int* __restrict__ tok_list, float* __restrict__ w_list,
    int* __restrict__ inv)
{
  __shared__ int lcnt[8], lbase[8];
  int tid = threadIdx.x;
  if (tid < 8) lcnt[tid] = 0;
  __syncthreads();
  int t = blockIdx.x * 256 + tid;
  int e1 = topE[2 * t], e2 = topE[2 * t + 1];
  float w1 = topW[2 * t], w2 = topW[2 * t + 1];
  int p1 = atomicAdd(&lcnt[e1], 1);
  int p2 = atomicAdd(&lcnt[e2], 1);
  __syncthreads();
  if (tid < 8) lbase[tid] = atomicAdd(&cnt[tid], lcnt[tid]);
  __syncthreads();
  int i1 = e1 * N_TOK + lbase[e1] + p1;
  int i2 = e2 * N_TOK + lbase[e2] + p2;
  tok_list[i1] = t; w_list[i1] = w1;
  tok_list[i2] = t; w_list[i2] = w2;
  inv[2 * t] = i1;
  inv[2 * t + 1] = i2;
}

__global__ void scan_kernel(const int* __restrict__ cnt, int* __restrict__ base)
{
  if (threadIdx.x == 0) {
    int s = 0;
    for (int e = 0; e < 8; ++e) { base[e] = s; s += cnt[e]; }
    base[8] = s;
  }
}

// ---------------------------------------------------------------- gather x rows -> bf16 slots
__global__ __launch_bounds__(256) void gather_cvt(
    const float* __restrict__ x, const int* __restrict__ tok_list,
    const int* __restrict__ base, bf16* __restrict__ xg)
{
  int wave = threadIdx.x >> 6, lane = threadIdx.x & 63;
  int s = blockIdx.x * 4 + wave;
  int e = 0;
#pragma unroll
  for (int i = 1; i < 8; ++i) e += (s >= base[i]);
  int tok = tok_list[e * N_TOK + (s - base[e])];
  const float4* src = (const float4*)(x + (size_t)tok * DIM);
  bf16x4* dst = (bf16x4*)(xg + (size_t)s * DIM);
#pragma unroll
  for (int i = 0; i < DIM / 256; ++i) {
    float4 v = src[i * 64 + lane];
    bf16x4 o;
    o.x = (bf16)v.x; o.y = (bf16)v.y; o.z = (bf16)v.z; o.w = (bf16)v.w;
    dst[i * 64 + lane] = o;
  }
}

// ---------------------------------------------------------------- transpose + f32->bf16
// src: [E][R][C] f32 -> dst: [E][C][R] bf16 ; pad 68 so read side is ds_read_b64
__global__ __launch_bounds__(256) void transpose_cvt(
    const float* __restrict__ src, bf16* __restrict__ dst, int R, int C)
{
  __shared__ bf16 tile[64][68];
  int e = blockIdx.z;
  const float* s = src + (size_t)e * R * C;
  bf16* d = dst + (size_t)e * R * C;
  int c0 = blockIdx.x * 64, r0 = blockIdx.y * 64;
  int tid = threadIdx.x;
  int rr = tid >> 4;          // 0..15
  int cc = (tid & 15) * 4;    // 0,4,..,60
#pragma unroll
  for (int i = 0; i < 4; ++i) {
    int r = i * 16 + rr;
    float4 v = *(const float4*)(s + (size_t)(r0 + r) * C + c0 + cc);
    tile[cc + 0][r] = (bf16)v.x;
    tile[cc + 1][r] = (bf16)v.y;
    tile[cc + 2][r] = (bf16)v.z;
    tile[cc + 3][r] = (bf16)v.w;
  }
  __syncthreads();
#pragma unroll
  for (int i = 0; i < 4; ++i) {
    int ct = i * 16 + rr;
    bf16x4 o = *(const bf16x4*)&tile[ct][cc];
    *(bf16x4*)(d + (size_t)(c0 + ct) * R + r0 + cc) = o;
  }
}

// ---------------------------------------------------------------- GEMM1: h = relu(xg @ W1t^T + b1)
// 128x128 tile, BK=64, DOUBLE-buffered LDS (64KB) with COUNTED vmcnt pipeline:
// loads for tile t+1 stay in flight across both barriers (never vmcnt(0) in
// steady state). Raw s_barrier + explicit asm waitcnt (m201 discipline).
__global__ __launch_bounds__(256) void gemm1_kernel(
    const bf16* __restrict__ xg, const bf16* __restrict__ W1t,
    const float* __restrict__ b1, bf16* __restrict__ hbuf,
    const int* __restrict__ cnt, const int* __restrict__ base)
{
  int e = blockIdx.z;
  int M = cnt[e];
  int mt = blockIdx.y;
  if (mt * 128 >= M) return;        // uniform early-exit, before any barrier
  int nt = blockIdx.x;
  int b0 = base[e];

  __shared__ bf16 As[2][128 * 64];  // 2 x 16 KB
  __shared__ bf16 Bs[2][128 * 64];  // 2 x 16 KB

  int tid = threadIdx.x;
  int wave = tid >> 6, lane = tid & 63;
  int crow = lane >> 3;                       // 0..7 row-in-chunk
  int ck   = ((lane & 7) ^ crow) * 8;         // pre-swizzled k-elem offset

  const bf16* pA[4]; const bf16* pB[4];
#pragma unroll
  for (int i = 0; i < 4; ++i) {
    int ra = (wave * 4 + i) * 8 + crow;       // tile row 0..127
    int lm = min(mt * 128 + ra, M - 1);
    pA[i] = xg + (size_t)(b0 + lm) * DIM + ck;
    pB[i] = W1t + ((size_t)e * HID + nt * 128 + ra) * DIM + ck;
  }

  int wm = wave & 1, wn = wave >> 1;
  int quad = lane >> 4, lr = lane & 15;
  int sw = lr & 7;                            // read-side swizzle key
  f32x4 acc[4][4] = {};

  const int NKT = DIM / 64;                   // 16
  stage_tile(pA[0], pA[1], pA[2], pA[3], pB[0], pB[1], pB[2], pB[3],
             As[0], Bs[0], 0, wave);
  stage_tile(pA[0], pA[1], pA[2], pA[3], pB[0], pB[1], pB[2], pB[3],
             As[1], Bs[1], 64, wave);

  for (int kt = 0; kt < NKT; ++kt) {
    int cur = kt & 1;
    // wait ONLY for tile kt's 8 loads (8 newer stay in flight), then sync
    if (kt < NKT - 1) asm volatile("s_waitcnt vmcnt(8)" ::: "memory");
    else              asm volatile("s_waitcnt vmcnt(0)" ::: "memory");
    __builtin_amdgcn_sched_barrier(0);
    __builtin_amdgcn_s_barrier();
    __builtin_amdgcn_sched_barrier(0);

    const bf16* Asb = As[cur];
    const bf16* Bsb = Bs[cur];
#pragma unroll
    for (int kk = 0; kk < 2; ++kk) {
      bf16x8 af[4], bfr[4];
#pragma unroll
      for (int i = 0; i < 4; ++i)
        af[i] = *(const bf16x8*)(Asb + (wm * 64 + i * 16 + lr) * 64 + (((kk * 4 + quad) ^ sw) * 8));
#pragma unroll
      for (int j = 0; j < 4; ++j)
        bfr[j] = *(const bf16x8*)(Bsb + (wn * 64 + j * 16 + lr) * 64 + (((kk * 4 + quad) ^ sw) * 8));
#pragma unroll
      for (int i = 0; i < 4; ++i)
#pragma unroll
        for (int j = 0; j < 4; ++j)
          acc[i][j] = __builtin_amdgcn_mfma_f32_16x16x32_bf16(af[i], bfr[j], acc[i][j], 0, 0, 0);
    }

    // my LDS reads complete -> barrier -> safe to overwrite this buffer
    asm volatile("s_waitcnt lgkmcnt(0)" ::: "memory");
    __builtin_amdgcn_sched_barrier(0);
    __builtin_amdgcn_s_barrier();
    __builtin_amdgcn_sched_barrier(0);
    if (kt + 2 < NKT)
      stage_tile(pA[0], pA[1], pA[2], pA[3], pB[0], pB[1], pB[2], pB[3],
                 As[cur], Bs[cur], (kt + 2) * 64, wave);
  }

#pragma unroll
  for (int j = 0; j < 4; ++j) {
    int col = nt * 128 + wn * 64 + j * 16 + lr;
    float bias = b1[e * HID + col];
#pragma unroll
    for (int i = 0; i < 4; ++i) {
#pragma unroll
      for (int r = 0; r < 4; ++r) {
        int lm = mt * 128 + wm * 64 + i * 16 + quad * 4 + r;
        if (lm < M) {
          float v = acc[i][j][r] + bias;
          hbuf[(size_t)(b0 + lm) * HID + col] = (bf16)fmaxf(v, 0.f);
        }
      }
    }
  }
}

// ---------------------------------------------------------------- GEMM2: ybuf[slot] = h[slot] @ W2t^T + b2
// same counted-vmcnt depth-2 pipeline; plain f32 stores, no atomics
__global__ __launch_bounds__(256) void gemm2_kernel(
    const bf16* __restrict__ hbuf, const bf16* __restrict__ W2t,
    const float* __restrict__ b2, float* __restrict__ ybufA, float* __restrict__ ybufB,
    const int* __restrict__ cnt, const int* __restrict__ base)
{
  int e = blockIdx.z;
  int M = cnt[e];
  int mt = blockIdx.y;
  if (mt * 128 >= M) return;
  int nt = blockIdx.x;
  int b0 = base[e];

  __shared__ bf16 As[2][128 * 64];
  __shared__ bf16 Bs[2][128 * 64];

  int tid = threadIdx.x;
  int wave = tid >> 6, lane = tid & 63;
  int crow = lane >> 3;
  int ck   = ((lane & 7) ^ crow) * 8;

  const bf16* pA[4]; const bf16* pB[4];
#pragma unroll
  for (int i = 0; i < 4; ++i) {
    int ra = (wave * 4 + i) * 8 + crow;
    int lm = min(mt * 128 + ra, M - 1);
    pA[i] = hbuf + (size_t)(b0 + lm) * HID + ck;
    pB[i] = W2t + ((size_t)e * OUTD + nt * 128 + ra) * HID + ck;
  }

  int wm = wave & 1, wn = wave >> 1;
  int quad = lane >> 4, lr = lane & 15;
  int sw = lr & 7;
  f32x4 acc[4][4] = {};

  const int NKT = HID / 64;                   // 64
  stage_tile(pA[0], pA[1], pA[2], pA[3], pB[0], pB[1], pB[2], pB[3],
             As[0], Bs[0], 0, wave);
  stage_tile(pA[0], pA[1], pA[2], pA[3], pB[0], pB[1], pB[2], pB[3],
             As[1], Bs[1], 64, wave);

  for (int kt = 0; kt < NKT; ++kt) {
    int cur = kt & 1;
    if (kt < NKT - 1) asm volatile("s_waitcnt vmcnt(8)" ::: "memory");
    else              asm volatile("s_waitcnt vmcnt(0)" ::: "memory");
    __builtin_amdgcn_sched_barrier(0);
    __builtin_amdgcn_s_barrier();
    __builtin_amdgcn_sched_barrier(0);

    const bf16* Asb = As[cur];
    const bf16* Bsb = Bs[cur];
#pragma unroll
    for (int kk = 0; kk < 2; ++kk) {
      bf16x8 af[4], bfr[4];
#pragma unroll
      for (int i = 0; i < 4; ++i)
        af[i] = *(const bf16x8*)(Asb + (wm * 64 + i * 16 + lr) * 64 + (((kk * 4 + quad) ^ sw) * 8));
#pragma unroll
      for (int j = 0; j < 4; ++j)
        bfr[j] = *(const bf16x8*)(Bsb + (wn * 64 + j * 16 + lr) * 64 + (((kk * 4 + quad) ^ sw) * 8));
#pragma unroll
      for (int i = 0; i < 4; ++i)
#pragma unroll
        for (int j = 0; j < 4; ++j)
          acc[i][j] = __builtin_amdgcn_mfma_f32_16x16x32_bf16(af[i], bfr[j], acc[i][j], 0, 0, 0);
    }

    asm volatile("s_waitcnt lgkmcnt(0)" ::: "memory");
    __builtin_amdgcn_sched_barrier(0);
    __builtin_amdgcn_s_barrier();
    __builtin_amdgcn_sched_barrier(0);
    if (kt + 2 < NKT)
      stage_tile(pA[0], pA[1], pA[2], pA[3], pB[0], pB[1], pB[2], pB[3],
                 As[cur], Bs[cur], (kt + 2) * 64, wave);
  }

#pragma unroll
  for (int j = 0; j < 4; ++j) {
    int col = nt * 128 + wn * 64 + j * 16 + lr;
    float bias = b2[e * OUTD + col];
#pragma unroll
    for (int i = 0; i < 4; ++i) {
#pragma unroll
      for (int r = 0; r < 4; ++r) {
        int lm = mt * 128 + wm * 64 + i * 16 + quad * 4 + r;
        if (lm < M) {
          int slot = b0 + lm;
          float* yr = (slot < 4096) ? (ybufA + (size_t)slot * OUTD)
                                    : (ybufB + (size_t)(slot - 4096) * OUTD);
          yr[col] = acc[i][j][r] + bias;
        }
      }
    }
  }
}

// ---------------------------------------------------------------- combine: out[t] = w0*y[slot0] + w1*y[slot1]
__global__ __launch_bounds__(256) void combine_kernel(
    const float* __restrict__ ybufA, const float* __restrict__ ybufB,
    const int* __restrict__ inv, const float* __restrict__ topW,
    const int* __restrict__ base, float* __restrict__ out)
{
  int wave = threadIdx.x >> 6, lane = threadIdx.x & 63;
  int t = blockIdx.x * 4 + wave;
  int i0 = inv[2 * t], i1 = inv[2 * t + 1];
  float w0 = topW[2 * t], w1 = topW[2 * t + 1];
  int s0 = base[i0 >> 12] + (i0 & (N_TOK - 1));
  int s1 = base[i1 >> 12] + (i1 & (N_TOK - 1));
  const float4* r0 = (const float4*)((s0 < 4096) ? (ybufA + (size_t)s0 * OUTD)
                                                 : (ybufB + (size_t)(s0 - 4096) * OUTD));
  const float4* r1 = (const float4*)((s1 < 4096) ? (ybufA + (size_t)s1 * OUTD)
                                                 : (ybufB + (size_t)(s1 - 4096) * OUTD));
  float4* o = (float4*)(out + (size_t)t * OUTD);
#pragma unroll
  for (int i = 0; i < OUTD / 256; ++i) {
    float4 a = r0[i * 64 + lane];
    float4 b = r1[i * 64 + lane];
    float4 c;
    c.x = w0 * a.x + w1 * b.x;
    c.y = w0 * a.y + w1 * b.y;
    c.z = w0 * a.z + w1 * b.z;
    c.w = w0 * a.w + w1 * b.w;
    o[i * 64 + lane] = c;
  }
}

// ---------------------------------------------------------------- launch
extern "C" void kernel_launch(void* const* d_in, const int* in_sizes, int n_in,
                              void* d_out, int out_size, void* d_ws, size_t ws_size,
                              hipStream_t stream)
{
  (void)in_sizes; (void)n_in; (void)ws_size; (void)out_size;
  const float* x  = (const float*)d_in[0];
  const float* W1 = (const float*)d_in[1];
  const float* b1 = (const float*)d_in[2];
  const float* W2 = (const float*)d_in[3];
  const float* b2 = (const float*)d_in[4];
  const float* Wg = (const float*)d_in[5];
  const float* bg = (const float*)d_in[6];
  float* out = (float*)d_out;

  char* ws = (char*)d_ws;
  // ws layout (bytes):
  //   0         tok_list   8*4096*4     = 131072
  //   131072    w_list                  = 131072
  //   262144    topE       4096*2*4     = 32768
  //   294912    topW                    = 32768
  //   327680    cnt        (64B pad)
  //   327744    base       (64B pad)
  //   327808    inv        4096*2*4     = 32768
  //   393216    xg         16MB   (ends 17170432)
  //   17170432  W1t        64MB   (ends 84279296)
  //   84279296  hbuf       64MB   (ends 151388160)
  //   W2t overlays [393216, 67502080) -- xg/W1t-head dead after gemm1
  //   ybufA 16MB at 67502080  (W1t tail hole, dead during gemm2)
  //   ybufB 16MB at 151388160 (ends 168165376)
  int*   tok_list = (int*)(ws + 0);
  float* w_list   = (float*)(ws + 131072);
  int*   topE     = (int*)(ws + 262144);
  float* topW     = (float*)(ws + 294912);
  int*   cnt      = (int*)(ws + 327680);
  int*   base     = (int*)(ws + 327744);
  int*   inv      = (int*)(ws + 327808);
  bf16*  xg    = (bf16*)(ws + 393216);
  bf16*  W1t   = (bf16*)(ws + 17170432);
  bf16*  hbuf  = (bf16*)(ws + 84279296);
  bf16*  W2t   = (bf16*)(ws + 393216);
  float* ybufA = (float*)(ws + 67502080);
  float* ybufB = (float*)(ws + 151388160);

  hipMemsetAsync(cnt, 0, 64, stream);

  gate_kernel<<<dim3(N_TOK / 4), 256, 0, stream>>>(x, Wg, bg, topE, topW);
  build_lists<<<dim3(N_TOK / 256), 256, 0, stream>>>(topE, topW, cnt, tok_list, w_list, inv);
  scan_kernel<<<dim3(1), 64, 0, stream>>>(cnt, base);
  gather_cvt<<<dim3(2 * N_TOK / 4), 256, 0, stream>>>(x, tok_list, base, xg);
  transpose_cvt<<<dim3(HID / 64, DIM / 64, NEXP), 256, 0, stream>>>(W1, W1t, DIM, HID);
  gemm1_kernel<<<dim3(HID / 128, N_TOK / 128, NEXP), 256, 0, stream>>>(xg, W1t, b1, hbuf, cnt, base);
  transpose_cvt<<<dim3(OUTD / 64, HID / 64, NEXP), 256, 0, stream>>>(W2, W2t, HID, OUTD);
  gemm2_kernel<<<dim3(OUTD / 128, N_TOK / 128, NEXP), 256, 0, stream>>>(hbuf, W2t, b2, ybufA, ybufB, cnt, base);
  combine_kernel<<<dim3(N_TOK / 4), 256, 0, stream>>>(ybufA, ybufB, inv, topW, base, out);
}

// Round 7
// 587.212 us; speedup vs baseline: 1.1117x; 1.0945x over previous
//
#include <hip/hip_runtime.h>
#include <hip/hip_bf16.h>
#include <cstdint>

typedef __bf16 bf16;
typedef bf16 bf16x8 __attribute__((ext_vector_type(8)));
typedef bf16 bf16x4 __attribute__((ext_vector_type(4)));
typedef float f32x4 __attribute__((ext_vector_type(4)));

#define N_TOK 4096
#define DIM   1024
#define HID   4096
#define OUTD  1024
#define NEXP  8

// ---------------------------------------------------------------- helpers
__device__ __forceinline__ void async_copy16(const void* g, void* l) {
  __builtin_amdgcn_global_load_lds(
      (const __attribute__((address_space(1))) void*)g,
      (__attribute__((address_space(3))) void*)l, 16, 0, 0);
}

// ---------------------------------------------------------------- gating
__global__ __launch_bounds__(256) void gate_kernel(
    const float* __restrict__ x, const float* __restrict__ Wg,
    const float* __restrict__ bg, int* __restrict__ topE, float* __restrict__ topW)
{
  int wave = threadIdx.x >> 6, lane = threadIdx.x & 63;
  int t = blockIdx.x * 4 + wave;
  float acc[8];
#pragma unroll
  for (int e = 0; e < 8; ++e) acc[e] = 0.f;
  const float* xrow = x + (size_t)t * DIM;
#pragma unroll
  for (int i = 0; i < DIM / 64; ++i) {
    int d = i * 64 + lane;
    float xv = xrow[d];
    float4 w0 = *(const float4*)(Wg + d * 8);
    float4 w1 = *(const float4*)(Wg + d * 8 + 4);
    acc[0] += xv * w0.x; acc[1] += xv * w0.y; acc[2] += xv * w0.z; acc[3] += xv * w0.w;
    acc[4] += xv * w1.x; acc[5] += xv * w1.y; acc[6] += xv * w1.z; acc[7] += xv * w1.w;
  }
#pragma unroll
  for (int off = 32; off > 0; off >>= 1) {
#pragma unroll
    for (int e = 0; e < 8; ++e) acc[e] += __shfl_xor(acc[e], off, 64);
  }
  if (lane == 0) {
    float l[8];
#pragma unroll
    for (int e = 0; e < 8; ++e) l[e] = acc[e] + bg[e];
    int e1 = 0;
#pragma unroll
    for (int e = 1; e < 8; ++e) if (l[e] > l[e1]) e1 = e;
    int e2 = (e1 == 0) ? 1 : 0;
#pragma unroll
    for (int e = 0; e < 8; ++e) if (e != e1 && l[e] > l[e2]) e2 = e;
    float w1 = 1.f / (1.f + __expf(l[e2] - l[e1]));
    topE[t * 2] = e1; topE[t * 2 + 1] = e2;
    topW[t * 2] = w1; topW[t * 2 + 1] = 1.f - w1;
  }
}

// ---------------------------------------------------------------- routing lists
__global__ __launch_bounds__(256) void build_lists(
    const int* __restrict__ topE, const float* __restrict__ topW,
    int* __restrict__ cnt, int* __restrict__ tok_list, float* __restrict__ w_list,
    int* __restrict__ inv)
{
  __shared__ int lcnt[8], lbase[8];
  int tid = threadIdx.x;
  if (tid < 8) lcnt[tid] = 0;
  __syncthreads();
  int t = blockIdx.x * 256 + tid;
  int e1 = topE[2 * t], e2 = topE[2 * t + 1];
  float w1 = topW[2 * t], w2 = topW[2 * t + 1];
  int p1 = atomicAdd(&lcnt[e1], 1);
  int p2 = atomicAdd(&lcnt[e2], 1);
  __syncthreads();
  if (tid < 8) lbase[tid] = atomicAdd(&cnt[tid], lcnt[tid]);
  __syncthreads();
  int i1 = e1 * N_TOK + lbase[e1] + p1;
  int i2 = e2 * N_TOK + lbase[e2] + p2;
  tok_list[i1] = t; w_list[i1] = w1;
  tok_list[i2] = t; w_list[i2] = w2;
  inv[2 * t] = i1;
  inv[2 * t + 1] = i2;
}

__global__ void scan_kernel(const int* __restrict__ cnt, int* __restrict__ base)
{
  if (threadIdx.x == 0) {
    int s = 0;
    for (int e = 0; e < 8; ++e) { base[e] = s; s += cnt[e]; }
    base[8] = s;
  }
}

// ---------------------------------------------------------------- gather x rows -> bf16 slots
__global__ __launch_bounds__(256) void gather_cvt(
    const float* __restrict__ x, const int* __restrict__ tok_list,
    const int* __restrict__ base, bf16* __restrict__ xg)
{
  int wave = threadIdx.x >> 6, lane = threadIdx.x & 63;
  int s = blockIdx.x * 4 + wave;
  int e = 0;
#pragma unroll
  for (int i = 1; i < 8; ++i) e += (s >= base[i]);
  int tok = tok_list[e * N_TOK + (s - base[e])];
  const float4* src = (const float4*)(x + (size_t)tok * DIM);
  bf16x4* dst = (bf16x4*)(xg + (size_t)s * DIM);
#pragma unroll
  for (int i = 0; i < DIM / 256; ++i) {
    float4 v = src[i * 64 + lane];
    bf16x4 o;
    o.x = (bf16)v.x; o.y = (bf16)v.y; o.z = (bf16)v.z; o.w = (bf16)v.w;
    dst[i * 64 + lane] = o;
  }
}

// ---------------------------------------------------------------- transpose + f32->bf16
// src: [E][R][C] f32 -> dst: [E][C][R] bf16 ; pad 68 so read side is ds_read_b64
__global__ __launch_bounds__(256) void transpose_cvt(
    const float* __restrict__ src, bf16* __restrict__ dst, int R, int C)
{
  __shared__ bf16 tile[64][68];
  int e = blockIdx.z;
  const float* s = src + (size_t)e * R * C;
  bf16* d = dst + (size_t)e * R * C;
  int c0 = blockIdx.x * 64, r0 = blockIdx.y * 64;
  int tid = threadIdx.x;
  int rr = tid >> 4;          // 0..15
  int cc = (tid & 15) * 4;    // 0,4,..,60
#pragma unroll
  for (int i = 0; i < 4; ++i) {
    int r = i * 16 + rr;
    float4 v = *(const float4*)(s + (size_t)(r0 + r) * C + c0 + cc);
    tile[cc + 0][r] = (bf16)v.x;
    tile[cc + 1][r] = (bf16)v.y;
    tile[cc + 2][r] = (bf16)v.z;
    tile[cc + 3][r] = (bf16)v.w;
  }
  __syncthreads();
#pragma unroll
  for (int i = 0; i < 4; ++i) {
    int ct = i * 16 + rr;
    bf16x4 o = *(const bf16x4*)&tile[ct][cc];
    *(bf16x4*)(d + (size_t)(c0 + ct) * R + r0 + cc) = o;
  }
}

// ---------------------------------------------------------------- GEMM1: h = relu(xg @ W1t^T + b1)
// 128x128 tile, BK=32, 16KB LDS, R2 sync structure, 8 WAVES (512 threads):
// wave (wm=w&3, wn=w>>2) owns a 32x64 sub-tile; acc 2x4 frags.
// Staging: 1 A + 1 B async_copy16 per thread; wave w stages rows w*16..w*16+15.
__global__ __launch_bounds__(512) void gemm1_kernel(
    const bf16* __restrict__ xg, const bf16* __restrict__ W1t,
    const float* __restrict__ b1, bf16* __restrict__ hbuf,
    const int* __restrict__ cnt, const int* __restrict__ base)
{
  int e = blockIdx.z;
  int M = cnt[e];
  int mt = blockIdx.y;
  if (mt * 128 >= M) return;
  int nt = blockIdx.x;
  int b0 = base[e];

  __shared__ bf16 As[128 * 32];   // 8 KB
  __shared__ bf16 Bs[128 * 32];   // 8 KB

  int tid = threadIdx.x;
  int wave = tid >> 6, lane = tid & 63;

  int sr = wave * 16 + (lane >> 2);   // stage row 0..127
  int ko = (lane & 3) * 8;            // k elem offset 0/8/16/24
  int lmA = min(mt * 128 + sr, M - 1);
  const bf16* gA = xg + (size_t)(b0 + lmA) * DIM + ko;
  const bf16* gB = W1t + ((size_t)e * HID + nt * 128 + sr) * DIM + ko;
  bf16* lA = As + wave * 512;         // wave-uniform LDS base (HW adds lane*16B)
  bf16* lB = Bs + wave * 512;

  int wm = wave & 3, wn = wave >> 2;  // 4 m-strips x 2 n-strips
  int quad = lane >> 4, lr = lane & 15;
  f32x4 acc[2][4] = {};

  for (int kt = 0; kt < DIM / 32; ++kt) {
    int kofs = kt * 32;
    async_copy16(gA + kofs, lA);
    async_copy16(gB + kofs, lB);
    __syncthreads();
    bf16x8 af[2], bfr[4];
#pragma unroll
    for (int i = 0; i < 2; ++i)
      af[i] = *(const bf16x8*)(As + (wm * 32 + i * 16 + lr) * 32 + quad * 8);
#pragma unroll
    for (int j = 0; j < 4; ++j)
      bfr[j] = *(const bf16x8*)(Bs + (wn * 64 + j * 16 + lr) * 32 + quad * 8);
#pragma unroll
    for (int i = 0; i < 2; ++i)
#pragma unroll
      for (int j = 0; j < 4; ++j)
        acc[i][j] = __builtin_amdgcn_mfma_f32_16x16x32_bf16(af[i], bfr[j], acc[i][j], 0, 0, 0);
    __syncthreads();
  }

#pragma unroll
  for (int j = 0; j < 4; ++j) {
    int col = nt * 128 + wn * 64 + j * 16 + lr;
    float bias = b1[e * HID + col];
#pragma unroll
    for (int i = 0; i < 2; ++i) {
#pragma unroll
      for (int r = 0; r < 4; ++r) {
        int lm = mt * 128 + wm * 32 + i * 16 + quad * 4 + r;
        if (lm < M) {
          float v = acc[i][j][r] + bias;
          hbuf[(size_t)(b0 + lm) * HID + col] = (bf16)fmaxf(v, 0.f);
        }
      }
    }
  }
}

// ---------------------------------------------------------------- GEMM2: ybuf[slot] = h[slot] @ W2t^T + b2
// same 8-wave 512-thread structure; plain f32 stores, no atomics
__global__ __launch_bounds__(512) void gemm2_kernel(
    const bf16* __restrict__ hbuf, const bf16* __restrict__ W2t,
    const float* __restrict__ b2, float* __restrict__ ybufA, float* __restrict__ ybufB,
    const int* __restrict__ cnt, const int* __restrict__ base)
{
  int e = blockIdx.z;
  int M = cnt[e];
  int mt = blockIdx.y;
  if (mt * 128 >= M) return;
  int nt = blockIdx.x;
  int b0 = base[e];

  __shared__ bf16 As[128 * 32];
  __shared__ bf16 Bs[128 * 32];

  int tid = threadIdx.x;
  int wave = tid >> 6, lane = tid & 63;

  int sr = wave * 16 + (lane >> 2);
  int ko = (lane & 3) * 8;
  int lmA = min(mt * 128 + sr, M - 1);
  const bf16* gA = hbuf + (size_t)(b0 + lmA) * HID + ko;
  const bf16* gB = W2t + ((size_t)e * OUTD + nt * 128 + sr) * HID + ko;
  bf16* lA = As + wave * 512;
  bf16* lB = Bs + wave * 512;

  int wm = wave & 3, wn = wave >> 2;
  int quad = lane >> 4, lr = lane & 15;
  f32x4 acc[2][4] = {};

  for (int kt = 0; kt < HID / 32; ++kt) {
    int kofs = kt * 32;
    async_copy16(gA + kofs, lA);
    async_copy16(gB + kofs, lB);
    __syncthreads();
    bf16x8 af[2], bfr[4];
#pragma unroll
    for (int i = 0; i < 2; ++i)
      af[i] = *(const bf16x8*)(As + (wm * 32 + i * 16 + lr) * 32 + quad * 8);
#pragma unroll
    for (int j = 0; j < 4; ++j)
      bfr[j] = *(const bf16x8*)(Bs + (wn * 64 + j * 16 + lr) * 32 + quad * 8);
#pragma unroll
    for (int i = 0; i < 2; ++i)
#pragma unroll
      for (int j = 0; j < 4; ++j)
        acc[i][j] = __builtin_amdgcn_mfma_f32_16x16x32_bf16(af[i], bfr[j], acc[i][j], 0, 0, 0);
    __syncthreads();
  }

#pragma unroll
  for (int j = 0; j < 4; ++j) {
    int col = nt * 128 + wn * 64 + j * 16 + lr;
    float bias = b2[e * OUTD + col];
#pragma unroll
    for (int i = 0; i < 2; ++i) {
#pragma unroll
      for (int r = 0; r < 4; ++r) {
        int lm = mt * 128 + wm * 32 + i * 16 + quad * 4 + r;
        if (lm < M) {
          int slot = b0 + lm;
          float* yr = (slot < 4096) ? (ybufA + (size_t)slot * OUTD)
                                    : (ybufB + (size_t)(slot - 4096) * OUTD);
          yr[col] = acc[i][j][r] + bias;
        }
      }
    }
  }
}

// ---------------------------------------------------------------- combine: out[t] = w0*y[slot0] + w1*y[slot1]
__global__ __launch_bounds__(256) void combine_kernel(
    const float* __restrict__ ybufA, const float* __restrict__ ybufB,
    const int* __restrict__ inv, const float* __restrict__ topW,
    const int* __restrict__ base, float* __restrict__ out)
{
  int wave = threadIdx.x >> 6, lane = threadIdx.x & 63;
  int t = blockIdx.x * 4 + wave;
  int i0 = inv[2 * t], i1 = inv[2 * t + 1];
  float w0 = topW[2 * t], w1 = topW[2 * t + 1];
  int s0 = base[i0 >> 12] + (i0 & (N_TOK - 1));
  int s1 = base[i1 >> 12] + (i1 & (N_TOK - 1));
  const float4* r0 = (const float4*)((s0 < 4096) ? (ybufA + (size_t)s0 * OUTD)
                                                 : (ybufB + (size_t)(s0 - 4096) * OUTD));
  const float4* r1 = (const float4*)((s1 < 4096) ? (ybufA + (size_t)s1 * OUTD)
                                                 : (ybufB + (size_t)(s1 - 4096) * OUTD));
  float4* o = (float4*)(out + (size_t)t * OUTD);
#pragma unroll
  for (int i = 0; i < OUTD / 256; ++i) {
    float4 a = r0[i * 64 + lane];
    float4 b = r1[i * 64 + lane];
    float4 c;
    c.x = w0 * a.x + w1 * b.x;
    c.y = w0 * a.y + w1 * b.y;
    c.z = w0 * a.z + w1 * b.z;
    c.w = w0 * a.w + w1 * b.w;
    o[i * 64 + lane] = c;
  }
}

// ---------------------------------------------------------------- launch
extern "C" void kernel_launch(void* const* d_in, const int* in_sizes, int n_in,
                              void* d_out, int out_size, void* d_ws, size_t ws_size,
                              hipStream_t stream)
{
  (void)in_sizes; (void)n_in; (void)ws_size; (void)out_size;
  const float* x  = (const float*)d_in[0];
  const float* W1 = (const float*)d_in[1];
  const float* b1 = (const float*)d_in[2];
  const float* W2 = (const float*)d_in[3];
  const float* b2 = (const float*)d_in[4];
  const float* Wg = (const float*)d_in[5];
  const float* bg = (const float*)d_in[6];
  float* out = (float*)d_out;

  char* ws = (char*)d_ws;
  // ws layout (bytes):
  //   0         tok_list   8*4096*4     = 131072
  //   131072    w_list                  = 131072
  //   262144    topE       4096*2*4     = 32768
  //   294912    topW                    = 32768
  //   327680    cnt        (64B pad)
  //   327744    base       (64B pad)
  //   327808    inv        4096*2*4     = 32768
  //   393216    xg         16MB   (ends 17170432)
  //   17170432  W1t        64MB   (ends 84279296)
  //   84279296  hbuf       64MB   (ends 151388160)
  //   W2t overlays [393216, 67502080) -- xg/W1t-head dead after gemm1
  //   ybufA 16MB at 67502080  (W1t tail hole, dead during gemm2)
  //   ybufB 16MB at 151388160 (ends 168165376)
  int*   tok_list = (int*)(ws + 0);
  float* w_list   = (float*)(ws + 131072);
  int*   topE     = (int*)(ws + 262144);
  float* topW     = (float*)(ws + 294912);
  int*   cnt      = (int*)(ws + 327680);
  int*   base     = (int*)(ws + 327744);
  int*   inv      = (int*)(ws + 327808);
  bf16*  xg    = (bf16*)(ws + 393216);
  bf16*  W1t   = (bf16*)(ws + 17170432);
  bf16*  hbuf  = (bf16*)(ws + 84279296);
  bf16*  W2t   = (bf16*)(ws + 393216);
  float* ybufA = (float*)(ws + 67502080);
  float* ybufB = (float*)(ws + 151388160);

  hipMemsetAsync(cnt, 0, 64, stream);

  gate_kernel<<<dim3(N_TOK / 4), 256, 0, stream>>>(x, Wg, bg, topE, topW);
  build_lists<<<dim3(N_TOK / 256), 256, 0, stream>>>(topE, topW, cnt, tok_list, w_list, inv);
  scan_kernel<<<dim3(1), 64, 0, stream>>>(cnt, base);
  gather_cvt<<<dim3(2 * N_TOK / 4), 256, 0, stream>>>(x, tok_list, base, xg);
  transpose_cvt<<<dim3(HID / 64, DIM / 64, NEXP), 256, 0, stream>>>(W1, W1t, DIM, HID);
  gemm1_kernel<<<dim3(HID / 128, N_TOK / 128, NEXP), 512, 0, stream>>>(xg, W1t, b1, hbuf, cnt, base);
  transpose_cvt<<<dim3(OUTD / 64, HID / 64, NEXP), 256, 0, stream>>>(W2, W2t, HID, OUTD);
  gemm2_kernel<<<dim3(OUTD / 128, N_TOK / 128, NEXP), 512, 0, stream>>>(hbuf, W2t, b2, ybufA, ybufB, cnt, base);
  combine_kernel<<<dim3(N_TOK / 4), 256, 0, stream>>>(ybufA, ybufB, inv, topW, base, out);
}